// Round 9
// baseline (544.003 us; speedup 1.0000x reference)
//
#include <hip/hip_runtime.h>
#include <cmath>
#include <type_traits>

typedef __bf16 bf16;
typedef __attribute__((ext_vector_type(8))) __bf16 bf16x8;
typedef __attribute__((ext_vector_type(4))) __bf16 bf16x4;
typedef __attribute__((ext_vector_type(4))) float f32x4;

__device__ __forceinline__ unsigned f2s(float x) {
    unsigned u = __float_as_uint(x);
    return (u & 0x80000000u) ? ~u : (u | 0x80000000u);
}
__device__ __forceinline__ float s2f(unsigned s) {
    return (s & 0x80000000u) ? __uint_as_float(s & 0x7FFFFFFFu)
                             : __uint_as_float(~s);
}

// ---------------- combined weight prep ----------------
// Wt0/Wt1[M=256,K=256] bf16 transposed; Bct[32,256] bf16 from W2|rW2.
__global__ void prep_weights_kernel(const float* __restrict__ W0, const float* __restrict__ W1,
                                    const float* __restrict__ W2, const float* __restrict__ rW2,
                                    bf16* __restrict__ Wt0, bf16* __restrict__ Wt1,
                                    bf16* __restrict__ Bct) {
    const int idx = blockIdx.x * blockDim.x + threadIdx.x;
    if (idx < 65536) {
        const int k = idx >> 8, m = idx & 255;
        Wt0[m * 256 + k] = (bf16)W0[idx];
        Wt1[m * 256 + k] = (bf16)W1[idx];
    }
    if (idx < 8192) {
        const int m = idx >> 8, k = idx & 255;
        const float v = (m < 16) ? W2[k * 16 + m] : rW2[k * 16 + (m - 16)];
        Bct[idx] = (bf16)v;
    }
}

// ---------------- MFMA GEMM + fused el/er/elmax epilogue ----------------
// Fb[N,256](bf16) = A[N,256] @ B; each wave's 64x64 quadrant = one full head,
// so el/er row-dots reduce within the wave (16-lane groups).
template <typename AT>
__global__ __launch_bounds__(256) void gemm_mfma_fused(const AT* __restrict__ A,
                                                       const bf16* __restrict__ Bt,
                                                       bf16* __restrict__ Fb,
                                                       const float* __restrict__ al,
                                                       const float* __restrict__ ar,
                                                       float* __restrict__ el, float* __restrict__ er,
                                                       unsigned* __restrict__ elmax_u, int N) {
    constexpr int K = 256, BM = 128, BK = 32;
    constexpr int LDA = BK + 8;
    __shared__ bf16 As[BM * LDA];
    __shared__ bf16 Bs[BM * LDA];

    const int tid = threadIdx.x;
    const int wave = tid >> 6, lane = tid & 63;
    const int quad = lane >> 4, l16 = lane & 15;
    const int rowBase = blockIdx.y * BM;
    const int colBase = blockIdx.x * BM;
    const int m_base = (wave >> 1) * 64, n_base = (wave & 1) * 64;

    f32x4 acc[4][4] = {};

    const int sr = tid >> 1;
    const int seg = (tid & 1) << 4;

    for (int k0 = 0; k0 < K; k0 += BK) {
        {
            const int gr = rowBase + sr;
            if constexpr (std::is_same<AT, float>::value) {
                float4 f0 = {0,0,0,0}, f1 = {0,0,0,0}, f2 = {0,0,0,0}, f3 = {0,0,0,0};
                if (gr < N) {
                    const float4* Ag = (const float4*)(A + (long)gr * K + k0 + seg);
                    f0 = Ag[0]; f1 = Ag[1]; f2 = Ag[2]; f3 = Ag[3];
                }
                bf16x8 p0, p1;
                p0[0] = (bf16)f0.x; p0[1] = (bf16)f0.y; p0[2] = (bf16)f0.z; p0[3] = (bf16)f0.w;
                p0[4] = (bf16)f1.x; p0[5] = (bf16)f1.y; p0[6] = (bf16)f1.z; p0[7] = (bf16)f1.w;
                p1[0] = (bf16)f2.x; p1[1] = (bf16)f2.y; p1[2] = (bf16)f2.z; p1[3] = (bf16)f2.w;
                p1[4] = (bf16)f3.x; p1[5] = (bf16)f3.y; p1[6] = (bf16)f3.z; p1[7] = (bf16)f3.w;
                *(bf16x8*)&As[sr * LDA + seg] = p0;
                *(bf16x8*)&As[sr * LDA + seg + 8] = p1;
            } else {
                bf16x8 p0 = {}, p1 = {};
                if (gr < N) {
                    const bf16x8* Ag = (const bf16x8*)(A + (long)gr * K + k0 + seg);
                    p0 = Ag[0]; p1 = Ag[1];
                }
                *(bf16x8*)&As[sr * LDA + seg] = p0;
                *(bf16x8*)&As[sr * LDA + seg + 8] = p1;
            }
        }
        {
            const bf16x8* Bg = (const bf16x8*)(Bt + (long)(colBase + sr) * K + k0 + seg);
            *(bf16x8*)&Bs[sr * LDA + seg] = Bg[0];
            *(bf16x8*)&Bs[sr * LDA + seg + 8] = Bg[1];
        }
        __syncthreads();

        bf16x8 af[4], bfr[4];
#pragma unroll
        for (int mi = 0; mi < 4; mi++)
            af[mi] = *(const bf16x8*)&As[(m_base + mi * 16 + l16) * LDA + quad * 8];
#pragma unroll
        for (int ni = 0; ni < 4; ni++)
            bfr[ni] = *(const bf16x8*)&Bs[(n_base + ni * 16 + l16) * LDA + quad * 8];
#pragma unroll
        for (int mi = 0; mi < 4; mi++)
#pragma unroll
            for (int ni = 0; ni < 4; ni++)
                acc[mi][ni] = __builtin_amdgcn_mfma_f32_16x16x32_bf16(af[mi], bfr[ni], acc[mi][ni], 0, 0, 0);
        __syncthreads();
    }

    // C-write: C/D layout col=lane&15, row=quad*4+reg [m89-verified]
#pragma unroll
    for (int mi = 0; mi < 4; mi++) {
#pragma unroll
        for (int r = 0; r < 4; r++) {
            const int grow = rowBase + m_base + mi * 16 + quad * 4 + r;
            if (grow < N) {
#pragma unroll
                for (int ni = 0; ni < 4; ni++) {
                    Fb[(long)grow * 256 + colBase + n_base + ni * 16 + l16] = (bf16)acc[mi][ni][r];
                }
            }
        }
    }

    // fused el/er + elmax (this wave's quadrant = head's full 64 cols)
    const int head = (colBase + n_base) >> 6;
    float alv[4], arv[4];
#pragma unroll
    for (int ni = 0; ni < 4; ni++) {
        alv[ni] = al[head * 64 + ni * 16 + l16];
        arv[ni] = ar[head * 64 + ni * 16 + l16];
    }
    float mloc = -INFINITY;
#pragma unroll
    for (int mi = 0; mi < 4; mi++) {
#pragma unroll
        for (int r = 0; r < 4; r++) {
            float e_l = acc[mi][0][r] * alv[0] + acc[mi][1][r] * alv[1]
                      + acc[mi][2][r] * alv[2] + acc[mi][3][r] * alv[3];
            float e_r = acc[mi][0][r] * arv[0] + acc[mi][1][r] * arv[1]
                      + acc[mi][2][r] * arv[2] + acc[mi][3][r] * arv[3];
#pragma unroll
            for (int off = 1; off < 16; off <<= 1) {
                e_l += __shfl_xor(e_l, off);
                e_r += __shfl_xor(e_r, off);
            }
            const int grow = rowBase + m_base + mi * 16 + quad * 4 + r;
            if (l16 == 0 && grow < N) {
                el[grow * 4 + head] = e_l;
                er[grow * 4 + head] = e_r;
                mloc = fmaxf(mloc, e_l);
            }
        }
    }
#pragma unroll
    for (int off = 1; off < 64; off <<= 1) mloc = fmaxf(mloc, __shfl_xor(mloc, off));
    if (lane == 0) atomicMax(&elmax_u[head], f2s(mloc));
}

// ---------------- MFMA GEMM narrow (layer 2) + fused el/er/elmax -----------------
// C[N,32](fp32) = A[N,256](bf16) @ Bct^T; cols 0..15 = W2-out (feat), 16..31 = res.
__global__ __launch_bounds__(256) void gemm_mfma_n32_fused(const bf16* __restrict__ A,
                                                           const bf16* __restrict__ Bt,
                                                           float* __restrict__ C,
                                                           const float* __restrict__ al2,
                                                           const float* __restrict__ ar2,
                                                           float* __restrict__ el, float* __restrict__ er,
                                                           unsigned* __restrict__ elmax_u, int N) {
    constexpr int K = 256, BM = 128, BK = 32;
    constexpr int LDA = BK + 8;
    __shared__ bf16 As[BM * LDA];
    __shared__ bf16 Bs[32 * LDA];

    const int tid = threadIdx.x;
    const int wave = tid >> 6, lane = tid & 63;
    const int quad = lane >> 4, l16 = lane & 15;
    const int rowBase = blockIdx.x * BM;
    const int m_base = (wave >> 1) * 64, n_base = (wave & 1) * 16;

    f32x4 acc[4] = {};

    const int sr = tid >> 1;
    const int seg = (tid & 1) << 4;

    for (int k0 = 0; k0 < K; k0 += BK) {
        {
            const int gr = rowBase + sr;
            bf16x8 p0 = {}, p1 = {};
            if (gr < N) {
                const bf16x8* Ag = (const bf16x8*)(A + (long)gr * K + k0 + seg);
                p0 = Ag[0]; p1 = Ag[1];
            }
            *(bf16x8*)&As[sr * LDA + seg] = p0;
            *(bf16x8*)&As[sr * LDA + seg + 8] = p1;
        }
        if (tid < 64) {
            const int br = tid >> 1;
            const bf16x8* Bg = (const bf16x8*)(Bt + br * K + k0 + seg);
            *(bf16x8*)&Bs[br * LDA + seg] = Bg[0];
            *(bf16x8*)&Bs[br * LDA + seg + 8] = Bg[1];
        }
        __syncthreads();

        const bf16x8 bfr = *(const bf16x8*)&Bs[(n_base + l16) * LDA + quad * 8];
#pragma unroll
        for (int mi = 0; mi < 4; mi++) {
            const bf16x8 af = *(const bf16x8*)&As[(m_base + mi * 16 + l16) * LDA + quad * 8];
            acc[mi] = __builtin_amdgcn_mfma_f32_16x16x32_bf16(af, bfr, acc[mi], 0, 0, 0);
        }
        __syncthreads();
    }

#pragma unroll
    for (int mi = 0; mi < 4; mi++) {
#pragma unroll
        for (int r = 0; r < 4; r++) {
            const int grow = rowBase + m_base + mi * 16 + quad * 4 + r;
            if (grow < N) C[(long)grow * 32 + n_base + l16] = acc[mi][r];
        }
    }

    // fused el/er (only waves holding the W2-out columns, n_base==0)
    if (n_base == 0) {
        const float alv = al2[l16];
        const float arv = ar2[l16];
        float mloc = -INFINITY;
#pragma unroll
        for (int mi = 0; mi < 4; mi++) {
#pragma unroll
            for (int r = 0; r < 4; r++) {
                float e_l = acc[mi][r] * alv;
                float e_r = acc[mi][r] * arv;
#pragma unroll
                for (int off = 1; off < 16; off <<= 1) {
                    e_l += __shfl_xor(e_l, off);
                    e_r += __shfl_xor(e_r, off);
                }
                const int grow = rowBase + m_base + mi * 16 + quad * 4 + r;
                if (l16 == 0 && grow < N) {
                    el[grow] = e_l;
                    er[grow] = e_r;
                    mloc = fmaxf(mloc, e_l);
                }
            }
        }
#pragma unroll
        for (int off = 1; off < 64; off <<= 1) mloc = fmaxf(mloc, __shfl_xor(mloc, off));
        if (lane == 0) atomicMax(&elmax_u[8], f2s(mloc));
    }
}

// ---------------- CSR build ----------------

__global__ void count_deg_kernel(const int* __restrict__ dst, int* __restrict__ deg, int E) {
    const int e = blockIdx.x * blockDim.x + threadIdx.x;
    if (e >= E) return;
    atomicAdd(&deg[dst[e]], 1);
}

__global__ void scan_block_kernel(const int* __restrict__ deg, int* __restrict__ scanned,
                                  int* __restrict__ block_sums, int N) {
    __shared__ int smem[256];
    const int tid = threadIdx.x;
    const int base = blockIdx.x * 1024 + tid * 4;
    int v[4];
#pragma unroll
    for (int i = 0; i < 4; i++) v[i] = (base + i < N) ? deg[base + i] : 0;
    const int tsum = v[0] + v[1] + v[2] + v[3];
    smem[tid] = tsum;
    __syncthreads();
    int acc = tsum;
    for (int off = 1; off < 256; off <<= 1) {
        const int t = (tid >= off) ? smem[tid - off] : 0;
        __syncthreads();
        acc += t;
        smem[tid] = acc;
        __syncthreads();
    }
    if (tid == 255) block_sums[blockIdx.x] = acc;
    int run = acc - tsum;
#pragma unroll
    for (int i = 0; i < 4; i++) {
        if (base + i < N) scanned[base + i] = run;
        run += v[i];
    }
}

// single wave: exclusive-scan block sums; also inits the 12 elmax slots
__global__ void scan_sums_kernel(int* __restrict__ block_sums, unsigned* __restrict__ elmax_u, int nb) {
    const int tid = threadIdx.x;
    if (tid < 12) elmax_u[tid] = f2s(-INFINITY);
    const int orig = (tid < nb) ? block_sums[tid] : 0;
    int v = orig;
#pragma unroll
    for (int off = 1; off < 64; off <<= 1) {
        const int t = __shfl_up(v, off);
        if (tid >= off) v += t;
    }
    if (tid < nb) block_sums[tid] = v - orig;
}

__global__ void apply_offsets_kernel(const int* __restrict__ scanned, const int* __restrict__ block_sums,
                                     int* __restrict__ row_ptr, int* __restrict__ cursor, int N, int E) {
    const int i = blockIdx.x * blockDim.x + threadIdx.x;
    if (i < N) {
        const int v = scanned[i] + block_sums[i >> 10];
        row_ptr[i] = v;
        cursor[i] = v;
    }
    if (i == 0) row_ptr[N] = E;
}

__global__ void scatter_kernel(const int* __restrict__ src, const int* __restrict__ dst,
                               int* __restrict__ cursor, int* __restrict__ csr_src, int E) {
    const int e = blockIdx.x * blockDim.x + threadIdx.x;
    if (e >= E) return;
    const int pos = atomicAdd(&cursor[dst[e]], 1);
    csr_src[pos] = src[e];
}

// ---------------- attention weights: ONE pass, upper-bound shift -----------------
__device__ __forceinline__ float4 leaky4(float4 e) {
    e.x = (e.x >= 0.f) ? e.x : 0.2f * e.x;
    e.y = (e.y >= 0.f) ? e.y : 0.2f * e.y;
    e.z = (e.z >= 0.f) ? e.z : 0.2f * e.z;
    e.w = (e.w >= 0.f) ? e.w : 0.2f * e.w;
    return e;
}

__global__ void attn_weight4_onepass(const int* __restrict__ row_ptr, const int* __restrict__ csr_src,
                                     const float* __restrict__ el, const float* __restrict__ er,
                                     const unsigned* __restrict__ elmax_u,
                                     float* __restrict__ attn, float* __restrict__ inv_d, int N) {
    const int n = blockIdx.x * blockDim.x + threadIdx.x;
    if (n >= N) return;
    const float4 erd = ((const float4*)er)[n];
    const float4 mx = {s2f(elmax_u[0]), s2f(elmax_u[1]), s2f(elmax_u[2]), s2f(elmax_u[3])};
    const float4 shift = leaky4(make_float4(mx.x + erd.x, mx.y + erd.y, mx.z + erd.z, mx.w + erd.w));
    const int p0 = row_ptr[n], p1 = row_ptr[n + 1];
    const float4* el4 = (const float4*)el;
    float4* attn4 = (float4*)attn;

    float4 denom = {0.f, 0.f, 0.f, 0.f};
    for (int p = p0; p < p1; ++p) {
        const float4 es = el4[csr_src[p]];
        float4 e = leaky4(make_float4(es.x + erd.x, es.y + erd.y, es.z + erd.z, es.w + erd.w));
        e.x = expf(e.x - shift.x); e.y = expf(e.y - shift.y);
        e.z = expf(e.z - shift.z); e.w = expf(e.w - shift.w);
        attn4[p] = e;
        denom.x += e.x; denom.y += e.y; denom.z += e.z; denom.w += e.w;
    }
    float4 inv = {(denom.x > 0.f) ? 1.f / denom.x : 0.f,
                  (denom.y > 0.f) ? 1.f / denom.y : 0.f,
                  (denom.z > 0.f) ? 1.f / denom.z : 0.f,
                  (denom.w > 0.f) ? 1.f / denom.w : 0.f};
    ((float4*)inv_d)[n] = inv;
}

__global__ void attn_weight1_onepass(const int* __restrict__ row_ptr, const int* __restrict__ csr_src,
                                     const float* __restrict__ el, const float* __restrict__ er,
                                     const unsigned* __restrict__ elmax_u,
                                     float* __restrict__ attn, float* __restrict__ inv_d, int N) {
    const int n = blockIdx.x * blockDim.x + threadIdx.x;
    if (n >= N) return;
    const float mx = s2f(elmax_u[8]);
    const float erd = er[n];
    float sh = mx + erd;
    sh = (sh >= 0.f) ? sh : 0.2f * sh;
    const int p0 = row_ptr[n], p1 = row_ptr[n + 1];
    float denom = 0.f;
    for (int p = p0; p < p1; ++p) {
        float e = el[csr_src[p]] + erd;
        e = (e >= 0.f) ? e : 0.2f * e;
        const float w = expf(e - sh);
        attn[p] = w;
        denom += w;
    }
    inv_d[n] = (denom > 0.f) ? 1.f / denom : 0.f;
}

// ---------------- aggregate: one WAVE per node, 4-edge unroll, applies inv_denom --
template <int H, int D, bool ACT, typename RT, typename OT>
__global__ void gat_aggregate_wave(const int* __restrict__ row_ptr, const int* __restrict__ csr_src,
                                   const float* __restrict__ attn, const float* __restrict__ inv_d,
                                   const bf16* __restrict__ feat,
                                   const RT* __restrict__ res, const float* __restrict__ bias,
                                   OT* __restrict__ out, int N) {
    constexpr int C = H * D;       // 256
    constexpr int V = C / 4;       // 64 x 4-channel groups
    const int wave = threadIdx.x >> 6;
    const int lane = threadIdx.x & 63;
    int n = blockIdx.x * (blockDim.x >> 6) + wave;
    if (n >= N) return;
    n = __builtin_amdgcn_readfirstlane(n);
    const int h = (lane * 4) / D;
    const bf16x4* feat4 = (const bf16x4*)feat;

    float4 acc = {0.f, 0.f, 0.f, 0.f};
    int p = row_ptr[n];
    const int pend = row_ptr[n + 1];
    for (; p + 4 <= pend; p += 4) {
        const int s0 = csr_src[p + 0];
        const int s1 = csr_src[p + 1];
        const int s2 = csr_src[p + 2];
        const int s3 = csr_src[p + 3];
        const float w0 = attn[(p + 0) * H + h];
        const float w1 = attn[(p + 1) * H + h];
        const float w2 = attn[(p + 2) * H + h];
        const float w3 = attn[(p + 3) * H + h];
        const bf16x4 f0 = feat4[(long)s0 * V + lane];
        const bf16x4 f1 = feat4[(long)s1 * V + lane];
        const bf16x4 f2 = feat4[(long)s2 * V + lane];
        const bf16x4 f3 = feat4[(long)s3 * V + lane];
        acc.x += w0 * (float)f0[0] + w1 * (float)f1[0] + w2 * (float)f2[0] + w3 * (float)f3[0];
        acc.y += w0 * (float)f0[1] + w1 * (float)f1[1] + w2 * (float)f2[1] + w3 * (float)f3[1];
        acc.z += w0 * (float)f0[2] + w1 * (float)f1[2] + w2 * (float)f2[2] + w3 * (float)f3[2];
        acc.w += w0 * (float)f0[3] + w1 * (float)f1[3] + w2 * (float)f2[3] + w3 * (float)f3[3];
    }
    for (; p < pend; ++p) {
        const int s = csr_src[p];
        const float w = attn[p * H + h];
        const bf16x4 f = feat4[(long)s * V + lane];
        acc.x += w * (float)f[0];
        acc.y += w * (float)f[1];
        acc.z += w * (float)f[2];
        acc.w += w * (float)f[3];
    }
    const float inv = inv_d[n * H + h];
    acc.x *= inv; acc.y *= inv; acc.z *= inv; acc.w *= inv;

    float4 r;
    if constexpr (std::is_same<RT, float>::value) {
        r = ((const float4*)res)[(long)n * V + lane];
    } else {
        const bf16x4 rb = ((const bf16x4*)res)[(long)n * V + lane];
        r = make_float4((float)rb[0], (float)rb[1], (float)rb[2], (float)rb[3]);
    }
    const float4 bb = ((const float4*)bias)[lane];
    float v[4] = {acc.x + r.x + bb.x, acc.y + r.y + bb.y,
                  acc.z + r.z + bb.z, acc.w + r.w + bb.w};
    if (ACT) {
#pragma unroll
        for (int i = 0; i < 4; i++) {
            const float sp = (v[i] > 20.f) ? v[i] : log1pf(expf(v[i]));
            v[i] = v[i] * tanhf(sp);
        }
    }
    if constexpr (std::is_same<OT, float>::value) {
        float4 o = {v[0], v[1], v[2], v[3]};
        ((float4*)out)[(long)n * V + lane] = o;
    } else {
        bf16x4 o;
        o[0] = (bf16)v[0]; o[1] = (bf16)v[1]; o[2] = (bf16)v[2]; o[3] = (bf16)v[3];
        ((bf16x4*)out)[(long)n * V + lane] = o;
    }
}

// ---------------- small-C aggregate (layer 2): thread per channel, 4-edge unroll --
template <int H, int D, bool ACT, int NPB>
__global__ void gat_aggregate_small(const int* __restrict__ row_ptr, const int* __restrict__ csr_src,
                                    const float* __restrict__ attn, const float* __restrict__ inv_d,
                                    const float* __restrict__ feat, int fstride,
                                    const float* __restrict__ res, int rstride,
                                    const float* __restrict__ bias, float* __restrict__ out, int N) {
    constexpr int C = H * D;
    const int local = threadIdx.x % C;
    const int n = blockIdx.x * NPB + threadIdx.x / C;
    if (n >= N) return;
    const int h = local / D;
    float acc = 0.f;
    int p = row_ptr[n];
    const int pend = row_ptr[n + 1];
    for (; p + 4 <= pend; p += 4) {
        const int s0 = csr_src[p + 0];
        const int s1 = csr_src[p + 1];
        const int s2 = csr_src[p + 2];
        const int s3 = csr_src[p + 3];
        const float w0 = attn[(p + 0) * H + h];
        const float w1 = attn[(p + 1) * H + h];
        const float w2 = attn[(p + 2) * H + h];
        const float w3 = attn[(p + 3) * H + h];
        acc += w0 * feat[(long)s0 * fstride + local] + w1 * feat[(long)s1 * fstride + local]
             + w2 * feat[(long)s2 * fstride + local] + w3 * feat[(long)s3 * fstride + local];
    }
    for (; p < pend; ++p) {
        const int s = csr_src[p];
        acc += attn[p * H + h] * feat[(long)s * fstride + local];
    }
    float v = acc * inv_d[n * H + h] + res[(long)n * rstride + local] + bias[local];
    if (ACT) {
        const float sp = (v > 20.f) ? v : log1pf(expf(v));
        v = v * tanhf(sp);
    }
    out[(long)n * C + local] = v;
}

// ---------------- host orchestration ----------------

static inline int cdiv(long a, long b) { return (int)((a + b - 1) / b); }

extern "C" void kernel_launch(void* const* d_in, const int* in_sizes, int n_in,
                              void* d_out, int out_size, void* d_ws, size_t ws_size,
                              hipStream_t stream) {
    const float* x   = (const float*)d_in[0];
    const int*   src = (const int*)d_in[1];
    const int*   dst = (const int*)d_in[2];
    const float* W0  = (const float*)d_in[3];
    const float* al0 = (const float*)d_in[4];
    const float* ar0 = (const float*)d_in[5];
    const float* b0  = (const float*)d_in[6];
    const float* W1  = (const float*)d_in[7];
    const float* al1 = (const float*)d_in[8];
    const float* ar1 = (const float*)d_in[9];
    const float* b1  = (const float*)d_in[10];
    const float* W2  = (const float*)d_in[11];
    const float* al2 = (const float*)d_in[12];
    const float* ar2 = (const float*)d_in[13];
    const float* b2  = (const float*)d_in[14];
    const float* rW2 = (const float*)d_in[15];
    float* out = (float*)d_out;

    const int N = in_sizes[0] / 256;   // 50000
    const int E = in_sizes[1];         // 800000

    // workspace layout
    bf16* Wt0    = (bf16*)d_ws;               // 256*256 bf16
    bf16* Wt1    = Wt0 + 65536;               // 256*256 bf16
    bf16* Bct    = Wt1 + 65536;               // 32*256 bf16
    bf16* Fb     = Bct + 8192;                // N*256 bf16 feat
    bf16* Hb     = Fb + (long)N * 256;        // N*256 bf16 hidden
    float* F2    = (float*)(Hb + (long)N * 256);  // N*32 (layer2 feat | res)
    float* el    = F2 + (long)N * 32;         // N*4
    float* er    = el + (long)N * 4;          // N*4
    float* inv_d = er + (long)N * 4;          // N*4
    float* attn  = inv_d + (long)N * 4;       // E*4
    unsigned* elmax_u = (unsigned*)(attn + (long)E * 4); // 12
    int* deg     = (int*)(elmax_u + 12);      // N
    int* scanned = deg + N;                   // N
    int* bsums   = scanned + N;               // 64
    int* row_ptr = bsums + 64;                // N+1
    int* cursor  = row_ptr + N + 1;           // N
    int* csr_src = cursor + N;                // E

    const int THREADS = 256;
    const int NB = cdiv(N, 1024);
    dim3 mfma_grid(2, cdiv(N, 128));

    // ---------- prep + CSR build (reused by all layers) ----------
    prep_weights_kernel<<<cdiv(65536, THREADS), THREADS, 0, stream>>>(W0, W1, W2, rW2, Wt0, Wt1, Bct);
    hipMemsetAsync(deg, 0, (size_t)N * 4, stream);
    count_deg_kernel<<<cdiv(E, THREADS), THREADS, 0, stream>>>(dst, deg, E);
    scan_block_kernel<<<NB, 256, 0, stream>>>(deg, scanned, bsums, N);
    scan_sums_kernel<<<1, 64, 0, stream>>>(bsums, elmax_u, NB);
    apply_offsets_kernel<<<cdiv(N, THREADS), THREADS, 0, stream>>>(scanned, bsums, row_ptr, cursor, N, E);
    scatter_kernel<<<cdiv(E, THREADS), THREADS, 0, stream>>>(src, dst, cursor, csr_src, E);

    // ================= Layer 0 (H=4, D=64), input x (fp32), out Hb (bf16) =========
    gemm_mfma_fused<float><<<mfma_grid, 256, 0, stream>>>(x, Wt0, Fb, al0, ar0, el, er, elmax_u, N);
    attn_weight4_onepass<<<cdiv(N, THREADS), THREADS, 0, stream>>>(row_ptr, csr_src, el, er, elmax_u, attn, inv_d, N);
    gat_aggregate_wave<4, 64, true, float, bf16><<<cdiv(N, 4), 256, 0, stream>>>(
        row_ptr, csr_src, attn, inv_d, Fb, x, b0, Hb, N);

    // ================= Layer 1 (H=4, D=64), input Hb (bf16), in-place =============
    gemm_mfma_fused<bf16><<<mfma_grid, 256, 0, stream>>>(Hb, Wt1, Fb, al1, ar1, el, er, elmax_u + 4, N);
    attn_weight4_onepass<<<cdiv(N, THREADS), THREADS, 0, stream>>>(row_ptr, csr_src, el, er, elmax_u + 4, attn, inv_d, N);
    gat_aggregate_wave<4, 64, true, bf16, bf16><<<cdiv(N, 4), 256, 0, stream>>>(
        row_ptr, csr_src, attn, inv_d, Fb, Hb, b1, Hb, N);

    // ================= Layer 2 (H=1, D=16): F2 = Hb @ [W2|rW2] =====================
    gemm_mfma_n32_fused<<<cdiv(N, 128), 256, 0, stream>>>(Hb, Bct, F2, al2, ar2, el, er, elmax_u, N);
    attn_weight1_onepass<<<cdiv(N, THREADS), THREADS, 0, stream>>>(row_ptr, csr_src, el, er, elmax_u, attn, inv_d, N);
    gat_aggregate_small<1, 16, false, 16><<<cdiv(N, 16), 256, 0, stream>>>(row_ptr, csr_src, attn, inv_d,
                                                                           F2, 32, F2 + 16, 32, b2, out, N);
}

// Round 10
// 505.051 us; speedup vs baseline: 1.0771x; 1.0771x over previous
//
#include <hip/hip_runtime.h>
#include <cmath>
#include <type_traits>

typedef __bf16 bf16;
typedef __attribute__((ext_vector_type(8))) __bf16 bf16x8;
typedef __attribute__((ext_vector_type(4))) __bf16 bf16x4;
typedef __attribute__((ext_vector_type(4))) float f32x4;

__device__ __forceinline__ unsigned f2s(float x) {
    unsigned u = __float_as_uint(x);
    return (u & 0x80000000u) ? ~u : (u | 0x80000000u);
}
__device__ __forceinline__ float s2f(unsigned s) {
    return (s & 0x80000000u) ? __uint_as_float(s & 0x7FFFFFFFu)
                             : __uint_as_float(~s);
}

// ---------------- combined weight prep ----------------
__global__ void prep_weights_kernel(const float* __restrict__ W0, const float* __restrict__ W1,
                                    const float* __restrict__ W2, const float* __restrict__ rW2,
                                    bf16* __restrict__ Wt0, bf16* __restrict__ Wt1,
                                    bf16* __restrict__ Bct) {
    const int idx = blockIdx.x * blockDim.x + threadIdx.x;
    if (idx < 65536) {
        const int k = idx >> 8, m = idx & 255;
        Wt0[m * 256 + k] = (bf16)W0[idx];
        Wt1[m * 256 + k] = (bf16)W1[idx];
    }
    if (idx < 8192) {
        const int m = idx >> 8, k = idx & 255;
        const float v = (m < 16) ? W2[k * 16 + m] : rW2[k * 16 + (m - 16)];
        Bct[idx] = (bf16)v;
    }
}

// ---------------- MFMA GEMM: Fb[N,256](bf16) = A[N,256] @ B (Bt bf16) ----
template <typename AT>
__global__ __launch_bounds__(256) void gemm_mfma_bf16(const AT* __restrict__ A,
                                                      const bf16* __restrict__ Bt,
                                                      bf16* __restrict__ Fb, int N) {
    constexpr int K = 256, BM = 128, BK = 32;
    constexpr int LDA = BK + 8;
    __shared__ bf16 As[BM * LDA];
    __shared__ bf16 Bs[BM * LDA];

    const int tid = threadIdx.x;
    const int wave = tid >> 6, lane = tid & 63;
    const int quad = lane >> 4, l16 = lane & 15;
    const int rowBase = blockIdx.y * BM;
    const int colBase = blockIdx.x * BM;
    const int m_base = (wave >> 1) * 64, n_base = (wave & 1) * 64;

    f32x4 acc[4][4] = {};

    const int sr = tid >> 1;
    const int seg = (tid & 1) << 4;

    for (int k0 = 0; k0 < K; k0 += BK) {
        {
            const int gr = rowBase + sr;
            if constexpr (std::is_same<AT, float>::value) {
                float4 f0 = {0,0,0,0}, f1 = {0,0,0,0}, f2 = {0,0,0,0}, f3 = {0,0,0,0};
                if (gr < N) {
                    const float4* Ag = (const float4*)(A + (long)gr * K + k0 + seg);
                    f0 = Ag[0]; f1 = Ag[1]; f2 = Ag[2]; f3 = Ag[3];
                }
                bf16x8 p0, p1;
                p0[0] = (bf16)f0.x; p0[1] = (bf16)f0.y; p0[2] = (bf16)f0.z; p0[3] = (bf16)f0.w;
                p0[4] = (bf16)f1.x; p0[5] = (bf16)f1.y; p0[6] = (bf16)f1.z; p0[7] = (bf16)f1.w;
                p1[0] = (bf16)f2.x; p1[1] = (bf16)f2.y; p1[2] = (bf16)f2.z; p1[3] = (bf16)f2.w;
                p1[4] = (bf16)f3.x; p1[5] = (bf16)f3.y; p1[6] = (bf16)f3.z; p1[7] = (bf16)f3.w;
                *(bf16x8*)&As[sr * LDA + seg] = p0;
                *(bf16x8*)&As[sr * LDA + seg + 8] = p1;
            } else {
                bf16x8 p0 = {}, p1 = {};
                if (gr < N) {
                    const bf16x8* Ag = (const bf16x8*)(A + (long)gr * K + k0 + seg);
                    p0 = Ag[0]; p1 = Ag[1];
                }
                *(bf16x8*)&As[sr * LDA + seg] = p0;
                *(bf16x8*)&As[sr * LDA + seg + 8] = p1;
            }
        }
        {
            const bf16x8* Bg = (const bf16x8*)(Bt + (long)(colBase + sr) * K + k0 + seg);
            *(bf16x8*)&Bs[sr * LDA + seg] = Bg[0];
            *(bf16x8*)&Bs[sr * LDA + seg + 8] = Bg[1];
        }
        __syncthreads();

        bf16x8 af[4], bfr[4];
#pragma unroll
        for (int mi = 0; mi < 4; mi++)
            af[mi] = *(const bf16x8*)&As[(m_base + mi * 16 + l16) * LDA + quad * 8];
#pragma unroll
        for (int ni = 0; ni < 4; ni++)
            bfr[ni] = *(const bf16x8*)&Bs[(n_base + ni * 16 + l16) * LDA + quad * 8];
#pragma unroll
        for (int mi = 0; mi < 4; mi++)
#pragma unroll
            for (int ni = 0; ni < 4; ni++)
                acc[mi][ni] = __builtin_amdgcn_mfma_f32_16x16x32_bf16(af[mi], bfr[ni], acc[mi][ni], 0, 0, 0);
        __syncthreads();
    }

    // epilogue: C/D layout col=lane&15, row=quad*4+reg [m89-verified]; write bf16
#pragma unroll
    for (int mi = 0; mi < 4; mi++) {
#pragma unroll
        for (int r = 0; r < 4; r++) {
            const int grow = rowBase + m_base + mi * 16 + quad * 4 + r;
            if (grow < N) {
#pragma unroll
                for (int ni = 0; ni < 4; ni++) {
                    Fb[(long)grow * 256 + colBase + n_base + ni * 16 + l16] = (bf16)acc[mi][ni][r];
                }
            }
        }
    }
}

// ---------------- MFMA GEMM narrow: C[N,32](fp32) = A[N,256](bf16) @ Bct^T --------
__global__ __launch_bounds__(256) void gemm_mfma_n32(const bf16* __restrict__ A,
                                                     const bf16* __restrict__ Bt,
                                                     float* __restrict__ C, int N) {
    constexpr int K = 256, BM = 128, BK = 32;
    constexpr int LDA = BK + 8;
    __shared__ bf16 As[BM * LDA];
    __shared__ bf16 Bs[32 * LDA];

    const int tid = threadIdx.x;
    const int wave = tid >> 6, lane = tid & 63;
    const int quad = lane >> 4, l16 = lane & 15;
    const int rowBase = blockIdx.x * BM;
    const int m_base = (wave >> 1) * 64, n_base = (wave & 1) * 16;

    f32x4 acc[4] = {};

    const int sr = tid >> 1;
    const int seg = (tid & 1) << 4;

    for (int k0 = 0; k0 < K; k0 += BK) {
        {
            const int gr = rowBase + sr;
            bf16x8 p0 = {}, p1 = {};
            if (gr < N) {
                const bf16x8* Ag = (const bf16x8*)(A + (long)gr * K + k0 + seg);
                p0 = Ag[0]; p1 = Ag[1];
            }
            *(bf16x8*)&As[sr * LDA + seg] = p0;
            *(bf16x8*)&As[sr * LDA + seg + 8] = p1;
        }
        if (tid < 64) {
            const int br = tid >> 1;
            const bf16x8* Bg = (const bf16x8*)(Bt + br * K + k0 + seg);
            *(bf16x8*)&Bs[br * LDA + seg] = Bg[0];
            *(bf16x8*)&Bs[br * LDA + seg + 8] = Bg[1];
        }
        __syncthreads();

        const bf16x8 bfr = *(const bf16x8*)&Bs[(n_base + l16) * LDA + quad * 8];
#pragma unroll
        for (int mi = 0; mi < 4; mi++) {
            const bf16x8 af = *(const bf16x8*)&As[(m_base + mi * 16 + l16) * LDA + quad * 8];
            acc[mi] = __builtin_amdgcn_mfma_f32_16x16x32_bf16(af, bfr, acc[mi], 0, 0, 0);
        }
        __syncthreads();
    }

#pragma unroll
    for (int mi = 0; mi < 4; mi++) {
#pragma unroll
        for (int r = 0; r < 4; r++) {
            const int grow = rowBase + m_base + mi * 16 + quad * 4 + r;
            if (grow < N) C[(long)grow * 32 + n_base + l16] = acc[mi][r];
        }
    }
}

// ---------------- el/er: one WAVE per node, all 4 heads ----------------
__global__ void el_er_node_kernel(const bf16* __restrict__ feat,
                                  const float* __restrict__ al, const float* __restrict__ ar,
                                  float* __restrict__ el, float* __restrict__ er, int N) {
    const int wid = (blockIdx.x * blockDim.x + threadIdx.x) >> 6;
    const int lane = threadIdx.x & 63;
    if (wid >= N) return;
    const bf16x4 f = ((const bf16x4*)feat)[(long)wid * 64 + lane];
    const float4 a = ((const float4*)al)[lane];
    const float4 b = ((const float4*)ar)[lane];
    const float f0 = (float)f[0], f1 = (float)f[1], f2 = (float)f[2], f3 = (float)f[3];
    float vl = f0 * a.x + f1 * a.y + f2 * a.z + f3 * a.w;
    float vr = f0 * b.x + f1 * b.y + f2 * b.z + f3 * b.w;
#pragma unroll
    for (int off = 1; off < 16; off <<= 1) {
        vl += __shfl_xor(vl, off);
        vr += __shfl_xor(vr, off);
    }
    if ((lane & 15) == 0) {
        const int h = lane >> 4;
        el[wid * 4 + h] = vl;
        er[wid * 4 + h] = vr;
    }
}

// el/er from fp32 feat with row stride (layer 2, H=1, D=16)
__global__ void el_er_strided16(const float* __restrict__ feat, int stride,
                                const float* __restrict__ al, const float* __restrict__ ar,
                                float* __restrict__ el, float* __restrict__ er, int N) {
    const int wid = (blockIdx.x * blockDim.x + threadIdx.x) >> 6;
    const int lane = threadIdx.x & 63;
    if (wid >= N) return;
    float vl = 0.f, vr = 0.f;
    if (lane < 16) {
        float f = feat[(long)wid * stride + lane];
        vl = f * al[lane];
        vr = f * ar[lane];
    }
#pragma unroll
    for (int off = 1; off < 16; off <<= 1) {
        vl += __shfl_xor(vl, off);
        vr += __shfl_xor(vr, off);
    }
    if (lane == 0) { el[wid] = vl; er[wid] = vr; }
}

// ---------------- global max of el (4 float-lanes) ----------------
__global__ void elmax4_kernel(const float4* __restrict__ el4, unsigned* __restrict__ elmax_u, int n4) {
    __shared__ float4 sm[256];
    float4 m = {-INFINITY, -INFINITY, -INFINITY, -INFINITY};
    for (int i = blockIdx.x * blockDim.x + threadIdx.x; i < n4; i += gridDim.x * blockDim.x) {
        const float4 v = el4[i];
        m.x = fmaxf(m.x, v.x); m.y = fmaxf(m.y, v.y);
        m.z = fmaxf(m.z, v.z); m.w = fmaxf(m.w, v.w);
    }
    sm[threadIdx.x] = m;
    __syncthreads();
    for (int off = 128; off > 0; off >>= 1) {
        if (threadIdx.x < off) {
            float4 o = sm[threadIdx.x + off];
            float4 c = sm[threadIdx.x];
            c.x = fmaxf(c.x, o.x); c.y = fmaxf(c.y, o.y);
            c.z = fmaxf(c.z, o.z); c.w = fmaxf(c.w, o.w);
            sm[threadIdx.x] = c;
        }
        __syncthreads();
    }
    if (threadIdx.x == 0) {
        const float4 r = sm[0];
        atomicMax(&elmax_u[0], f2s(r.x));
        atomicMax(&elmax_u[1], f2s(r.y));
        atomicMax(&elmax_u[2], f2s(r.z));
        atomicMax(&elmax_u[3], f2s(r.w));
    }
}

// ---------------- CSR build ----------------

__global__ void count_deg_kernel(const int* __restrict__ dst, int* __restrict__ deg, int E) {
    const int e = blockIdx.x * blockDim.x + threadIdx.x;
    if (e >= E) return;
    atomicAdd(&deg[dst[e]], 1);
}

__global__ void scan_block_kernel(const int* __restrict__ deg, int* __restrict__ scanned,
                                  int* __restrict__ block_sums, int N) {
    __shared__ int smem[256];
    const int tid = threadIdx.x;
    const int base = blockIdx.x * 1024 + tid * 4;
    int v[4];
#pragma unroll
    for (int i = 0; i < 4; i++) v[i] = (base + i < N) ? deg[base + i] : 0;
    const int tsum = v[0] + v[1] + v[2] + v[3];
    smem[tid] = tsum;
    __syncthreads();
    int acc = tsum;
    for (int off = 1; off < 256; off <<= 1) {
        const int t = (tid >= off) ? smem[tid - off] : 0;
        __syncthreads();
        acc += t;
        smem[tid] = acc;
        __syncthreads();
    }
    if (tid == 255) block_sums[blockIdx.x] = acc;
    int run = acc - tsum;
#pragma unroll
    for (int i = 0; i < 4; i++) {
        if (base + i < N) scanned[base + i] = run;
        run += v[i];
    }
}

// single wave: exclusive-scan block sums; also inits the 12 elmax slots
__global__ void scan_sums_kernel(int* __restrict__ block_sums, unsigned* __restrict__ elmax_u, int nb) {
    const int tid = threadIdx.x;
    if (tid < 12) elmax_u[tid] = f2s(-INFINITY);
    const int orig = (tid < nb) ? block_sums[tid] : 0;
    int v = orig;
#pragma unroll
    for (int off = 1; off < 64; off <<= 1) {
        const int t = __shfl_up(v, off);
        if (tid >= off) v += t;
    }
    if (tid < nb) block_sums[tid] = v - orig;
}

__global__ void apply_offsets_kernel(const int* __restrict__ scanned, const int* __restrict__ block_sums,
                                     int* __restrict__ row_ptr, int* __restrict__ cursor, int N, int E) {
    const int i = blockIdx.x * blockDim.x + threadIdx.x;
    if (i < N) {
        const int v = scanned[i] + block_sums[i >> 10];
        row_ptr[i] = v;
        cursor[i] = v;
    }
    if (i == 0) row_ptr[N] = E;
}

__global__ void scatter_kernel(const int* __restrict__ src, const int* __restrict__ dst,
                               int* __restrict__ cursor, int* __restrict__ csr_src, int E) {
    const int e = blockIdx.x * blockDim.x + threadIdx.x;
    if (e >= E) return;
    const int pos = atomicAdd(&cursor[dst[e]], 1);
    csr_src[pos] = src[e];
}

// ---------------- attention weights, WAVE-parallel ----------------
// One wave per node; lane = (edge-in-chunk, head): 16 edges x 4 heads per chunk.
// One-pass upper-bound shift: shift = leaky(el_max + er[d]) >= e (leaky monotonic),
// exp(e-shift) <= 1; softmax ratio identical. Stores unnormalized w + inv_denom.
__global__ void attn_weight4_wave(const int* __restrict__ row_ptr, const int* __restrict__ csr_src,
                                  const float* __restrict__ el, const float* __restrict__ er,
                                  const unsigned* __restrict__ elmax_u,
                                  float* __restrict__ attn, float* __restrict__ inv_d, int N) {
    const int wave = threadIdx.x >> 6;
    const int lane = threadIdx.x & 63;
    int n = blockIdx.x * (blockDim.x >> 6) + wave;
    if (n >= N) return;
    n = __builtin_amdgcn_readfirstlane(n);
    const int h = lane & 3;
    const int eo = lane >> 2;          // edge offset within 16-edge chunk
    const float erd = er[n * 4 + h];
    float sh = s2f(elmax_u[h]) + erd;
    sh = (sh >= 0.f) ? sh : 0.2f * sh;
    const int p0 = row_ptr[n], p1 = row_ptr[n + 1];
    float denom = 0.f;
    for (int base = p0; base < p1; base += 16) {
        const int p = base + eo;
        if (p < p1) {
            const int s = csr_src[p];
            float e = el[s * 4 + h] + erd;
            e = (e >= 0.f) ? e : 0.2f * e;
            const float w = expf(e - sh);
            attn[p * 4 + h] = w;
            denom += w;
        }
    }
    // reduce over lanes with same head (xor offsets preserve lane&3)
#pragma unroll
    for (int off = 4; off < 64; off <<= 1) denom += __shfl_xor(denom, off);
    if (lane < 4) inv_d[n * 4 + lane] = (denom > 0.f) ? 1.f / denom : 0.f;
}

// H=1: lane = edge-in-chunk (64 edges per chunk)
__global__ void attn_weight1_wave(const int* __restrict__ row_ptr, const int* __restrict__ csr_src,
                                  const float* __restrict__ el, const float* __restrict__ er,
                                  const unsigned* __restrict__ elmax_u,
                                  float* __restrict__ attn, float* __restrict__ inv_d, int N) {
    const int wave = threadIdx.x >> 6;
    const int lane = threadIdx.x & 63;
    int n = blockIdx.x * (blockDim.x >> 6) + wave;
    if (n >= N) return;
    n = __builtin_amdgcn_readfirstlane(n);
    const float mx = fmaxf(fmaxf(s2f(elmax_u[8]), s2f(elmax_u[9])),
                           fmaxf(s2f(elmax_u[10]), s2f(elmax_u[11])));
    const float erd = er[n];
    float sh = mx + erd;
    sh = (sh >= 0.f) ? sh : 0.2f * sh;
    const int p0 = row_ptr[n], p1 = row_ptr[n + 1];
    float denom = 0.f;
    for (int base = p0; base < p1; base += 64) {
        const int p = base + lane;
        if (p < p1) {
            float e = el[csr_src[p]] + erd;
            e = (e >= 0.f) ? e : 0.2f * e;
            const float w = expf(e - sh);
            attn[p] = w;
            denom += w;
        }
    }
#pragma unroll
    for (int off = 1; off < 64; off <<= 1) denom += __shfl_xor(denom, off);
    if (lane == 0) inv_d[n] = (denom > 0.f) ? 1.f / denom : 0.f;
}

// ---------------- aggregate: one WAVE per node, 4-edge unroll, applies inv_denom --
template <int H, int D, bool ACT, typename RT, typename OT>
__global__ void gat_aggregate_wave(const int* __restrict__ row_ptr, const int* __restrict__ csr_src,
                                   const float* __restrict__ attn, const float* __restrict__ inv_d,
                                   const bf16* __restrict__ feat,
                                   const RT* __restrict__ res, const float* __restrict__ bias,
                                   OT* __restrict__ out, int N) {
    constexpr int C = H * D;       // 256
    constexpr int V = C / 4;       // 64 x 4-channel groups
    const int wave = threadIdx.x >> 6;
    const int lane = threadIdx.x & 63;
    int n = blockIdx.x * (blockDim.x >> 6) + wave;
    if (n >= N) return;
    n = __builtin_amdgcn_readfirstlane(n);
    const int h = (lane * 4) / D;
    const bf16x4* feat4 = (const bf16x4*)feat;

    float4 acc = {0.f, 0.f, 0.f, 0.f};
    int p = row_ptr[n];
    const int pend = row_ptr[n + 1];
    for (; p + 4 <= pend; p += 4) {
        const int s0 = csr_src[p + 0];
        const int s1 = csr_src[p + 1];
        const int s2 = csr_src[p + 2];
        const int s3 = csr_src[p + 3];
        const float w0 = attn[(p + 0) * H + h];
        const float w1 = attn[(p + 1) * H + h];
        const float w2 = attn[(p + 2) * H + h];
        const float w3 = attn[(p + 3) * H + h];
        const bf16x4 f0 = feat4[(long)s0 * V + lane];
        const bf16x4 f1 = feat4[(long)s1 * V + lane];
        const bf16x4 f2 = feat4[(long)s2 * V + lane];
        const bf16x4 f3 = feat4[(long)s3 * V + lane];
        acc.x += w0 * (float)f0[0] + w1 * (float)f1[0] + w2 * (float)f2[0] + w3 * (float)f3[0];
        acc.y += w0 * (float)f0[1] + w1 * (float)f1[1] + w2 * (float)f2[1] + w3 * (float)f3[1];
        acc.z += w0 * (float)f0[2] + w1 * (float)f1[2] + w2 * (float)f2[2] + w3 * (float)f3[2];
        acc.w += w0 * (float)f0[3] + w1 * (float)f1[3] + w2 * (float)f2[3] + w3 * (float)f3[3];
    }
    for (; p < pend; ++p) {
        const int s = csr_src[p];
        const float w = attn[p * H + h];
        const bf16x4 f = feat4[(long)s * V + lane];
        acc.x += w * (float)f[0];
        acc.y += w * (float)f[1];
        acc.z += w * (float)f[2];
        acc.w += w * (float)f[3];
    }
    const float inv = inv_d[n * H + h];
    acc.x *= inv; acc.y *= inv; acc.z *= inv; acc.w *= inv;

    float4 r;
    if constexpr (std::is_same<RT, float>::value) {
        r = ((const float4*)res)[(long)n * V + lane];
    } else {
        const bf16x4 rb = ((const bf16x4*)res)[(long)n * V + lane];
        r = make_float4((float)rb[0], (float)rb[1], (float)rb[2], (float)rb[3]);
    }
    const float4 bb = ((const float4*)bias)[lane];
    float v[4] = {acc.x + r.x + bb.x, acc.y + r.y + bb.y,
                  acc.z + r.z + bb.z, acc.w + r.w + bb.w};
    if (ACT) {
#pragma unroll
        for (int i = 0; i < 4; i++) {
            const float sp = (v[i] > 20.f) ? v[i] : log1pf(expf(v[i]));
            v[i] = v[i] * tanhf(sp);
        }
    }
    if constexpr (std::is_same<OT, float>::value) {
        float4 o = {v[0], v[1], v[2], v[3]};
        ((float4*)out)[(long)n * V + lane] = o;
    } else {
        bf16x4 o;
        o[0] = (bf16)v[0]; o[1] = (bf16)v[1]; o[2] = (bf16)v[2]; o[3] = (bf16)v[3];
        ((bf16x4*)out)[(long)n * V + lane] = o;
    }
}

// ---------------- small-C aggregate (layer 2): thread per channel, 4-edge unroll --
template <int H, int D, bool ACT, int NPB>
__global__ void gat_aggregate_small(const int* __restrict__ row_ptr, const int* __restrict__ csr_src,
                                    const float* __restrict__ attn, const float* __restrict__ inv_d,
                                    const float* __restrict__ feat, int fstride,
                                    const float* __restrict__ res, int rstride,
                                    const float* __restrict__ bias, float* __restrict__ out, int N) {
    constexpr int C = H * D;
    const int local = threadIdx.x % C;
    const int n = blockIdx.x * NPB + threadIdx.x / C;
    if (n >= N) return;
    const int h = local / D;
    float acc = 0.f;
    int p = row_ptr[n];
    const int pend = row_ptr[n + 1];
    for (; p + 4 <= pend; p += 4) {
        const int s0 = csr_src[p + 0];
        const int s1 = csr_src[p + 1];
        const int s2 = csr_src[p + 2];
        const int s3 = csr_src[p + 3];
        const float w0 = attn[(p + 0) * H + h];
        const float w1 = attn[(p + 1) * H + h];
        const float w2 = attn[(p + 2) * H + h];
        const float w3 = attn[(p + 3) * H + h];
        acc += w0 * feat[(long)s0 * fstride + local] + w1 * feat[(long)s1 * fstride + local]
             + w2 * feat[(long)s2 * fstride + local] + w3 * feat[(long)s3 * fstride + local];
    }
    for (; p < pend; ++p) {
        const int s = csr_src[p];
        acc += attn[p * H + h] * feat[(long)s * fstride + local];
    }
    float v = acc * inv_d[n * H + h] + res[(long)n * rstride + local] + bias[local];
    if (ACT) {
        const float sp = (v > 20.f) ? v : log1pf(expf(v));
        v = v * tanhf(sp);
    }
    out[(long)n * C + local] = v;
}

// ---------------- host orchestration ----------------

static inline int cdiv(long a, long b) { return (int)((a + b - 1) / b); }

extern "C" void kernel_launch(void* const* d_in, const int* in_sizes, int n_in,
                              void* d_out, int out_size, void* d_ws, size_t ws_size,
                              hipStream_t stream) {
    const float* x   = (const float*)d_in[0];
    const int*   src = (const int*)d_in[1];
    const int*   dst = (const int*)d_in[2];
    const float* W0  = (const float*)d_in[3];
    const float* al0 = (const float*)d_in[4];
    const float* ar0 = (const float*)d_in[5];
    const float* b0  = (const float*)d_in[6];
    const float* W1  = (const float*)d_in[7];
    const float* al1 = (const float*)d_in[8];
    const float* ar1 = (const float*)d_in[9];
    const float* b1  = (const float*)d_in[10];
    const float* W2  = (const float*)d_in[11];
    const float* al2 = (const float*)d_in[12];
    const float* ar2 = (const float*)d_in[13];
    const float* b2  = (const float*)d_in[14];
    const float* rW2 = (const float*)d_in[15];
    float* out = (float*)d_out;

    const int N = in_sizes[0] / 256;   // 50000
    const int E = in_sizes[1];         // 800000

    // workspace layout
    bf16* Wt0    = (bf16*)d_ws;               // 256*256 bf16
    bf16* Wt1    = Wt0 + 65536;               // 256*256 bf16
    bf16* Bct    = Wt1 + 65536;               // 32*256 bf16
    bf16* Fb     = Bct + 8192;                // N*256 bf16 feat
    bf16* Hb     = Fb + (long)N * 256;        // N*256 bf16 hidden
    float* F2    = (float*)(Hb + (long)N * 256);  // N*32 (layer2 feat | res)
    float* el    = F2 + (long)N * 32;         // N*4
    float* er    = el + (long)N * 4;          // N*4
    float* inv_d = er + (long)N * 4;          // N*4
    float* attn  = inv_d + (long)N * 4;       // E*4
    unsigned* elmax_u = (unsigned*)(attn + (long)E * 4); // 12
    int* deg     = (int*)(elmax_u + 12);      // N
    int* scanned = deg + N;                   // N
    int* bsums   = scanned + N;               // 64
    int* row_ptr = bsums + 64;                // N+1
    int* cursor  = row_ptr + N + 1;           // N
    int* csr_src = cursor + N;                // E

    const int THREADS = 256;
    const int NB = cdiv(N, 1024);
    dim3 mfma_grid(2, cdiv(N, 128));

    // ---------- prep + CSR build (reused by all layers) ----------
    prep_weights_kernel<<<cdiv(65536, THREADS), THREADS, 0, stream>>>(W0, W1, W2, rW2, Wt0, Wt1, Bct);
    hipMemsetAsync(deg, 0, (size_t)N * 4, stream);
    count_deg_kernel<<<cdiv(E, THREADS), THREADS, 0, stream>>>(dst, deg, E);
    scan_block_kernel<<<NB, 256, 0, stream>>>(deg, scanned, bsums, N);
    scan_sums_kernel<<<1, 64, 0, stream>>>(bsums, elmax_u, NB);
    apply_offsets_kernel<<<cdiv(N, THREADS), THREADS, 0, stream>>>(scanned, bsums, row_ptr, cursor, N, E);
    scatter_kernel<<<cdiv(E, THREADS), THREADS, 0, stream>>>(src, dst, cursor, csr_src, E);

    // ================= Layer 0 (H=4, D=64), input x (fp32), out Hb (bf16) =========
    gemm_mfma_bf16<float><<<mfma_grid, 256, 0, stream>>>(x, Wt0, Fb, N);
    el_er_node_kernel<<<cdiv(N, 4), 256, 0, stream>>>(Fb, al0, ar0, el, er, N);
    elmax4_kernel<<<64, 256, 0, stream>>>((const float4*)el, elmax_u, N);
    attn_weight4_wave<<<cdiv(N, 4), 256, 0, stream>>>(row_ptr, csr_src, el, er, elmax_u, attn, inv_d, N);
    gat_aggregate_wave<4, 64, true, float, bf16><<<cdiv(N, 4), 256, 0, stream>>>(
        row_ptr, csr_src, attn, inv_d, Fb, x, b0, Hb, N);

    // ================= Layer 1 (H=4, D=64), input Hb (bf16), in-place =============
    gemm_mfma_bf16<bf16><<<mfma_grid, 256, 0, stream>>>(Hb, Wt1, Fb, N);
    el_er_node_kernel<<<cdiv(N, 4), 256, 0, stream>>>(Fb, al1, ar1, el, er, N);
    elmax4_kernel<<<64, 256, 0, stream>>>((const float4*)el, elmax_u + 4, N);
    attn_weight4_wave<<<cdiv(N, 4), 256, 0, stream>>>(row_ptr, csr_src, el, er, elmax_u + 4, attn, inv_d, N);
    gat_aggregate_wave<4, 64, true, bf16, bf16><<<cdiv(N, 4), 256, 0, stream>>>(
        row_ptr, csr_src, attn, inv_d, Fb, Hb, b1, Hb, N);

    // ================= Layer 2 (H=1, D=16): F2 = Hb @ [W2|rW2] =====================
    gemm_mfma_n32<<<cdiv(N, 128), 256, 0, stream>>>(Hb, Bct, F2, N);
    el_er_strided16<<<cdiv(N, 4), 256, 0, stream>>>(F2, 32, al2, ar2, el, er, N);
    elmax4_kernel<<<64, 256, 0, stream>>>((const float4*)el, elmax_u + 8, N / 4);
    attn_weight1_wave<<<cdiv(N, 4), 256, 0, stream>>>(row_ptr, csr_src, el, er, elmax_u, attn, inv_d, N);
    gat_aggregate_small<1, 16, false, 16><<<cdiv(N, 16), 256, 0, stream>>>(row_ptr, csr_src, attn, inv_d,
                                                                           F2, 32, F2 + 16, 32, b2, out, N);
}

// Round 11
// 477.607 us; speedup vs baseline: 1.1390x; 1.0575x over previous
//
#include <hip/hip_runtime.h>
#include <cmath>
#include <type_traits>

typedef __bf16 bf16;
typedef __attribute__((ext_vector_type(8))) __bf16 bf16x8;
typedef __attribute__((ext_vector_type(4))) __bf16 bf16x4;
typedef __attribute__((ext_vector_type(4))) float f32x4;

__device__ __forceinline__ unsigned f2s(float x) {
    unsigned u = __float_as_uint(x);
    return (u & 0x80000000u) ? ~u : (u | 0x80000000u);
}
__device__ __forceinline__ float s2f(unsigned s) {
    return (s & 0x80000000u) ? __uint_as_float(s & 0x7FFFFFFFu)
                             : __uint_as_float(~s);
}

// ---------------- combined weight prep ----------------
__global__ void prep_weights_kernel(const float* __restrict__ W0, const float* __restrict__ W1,
                                    const float* __restrict__ W2, const float* __restrict__ rW2,
                                    bf16* __restrict__ Wt0, bf16* __restrict__ Wt1,
                                    bf16* __restrict__ Bct) {
    const int idx = blockIdx.x * blockDim.x + threadIdx.x;
    if (idx < 65536) {
        const int k = idx >> 8, m = idx & 255;
        Wt0[m * 256 + k] = (bf16)W0[idx];
        Wt1[m * 256 + k] = (bf16)W1[idx];
    }
    if (idx < 8192) {
        const int m = idx >> 8, k = idx & 255;
        const float v = (m < 16) ? W2[k * 16 + m] : rW2[k * 16 + (m - 16)];
        Bct[idx] = (bf16)v;
    }
}

// ---------------- MFMA GEMM: Fb[N,256](bf16) = A[N,256] @ B (Bt bf16) ----
template <typename AT>
__global__ __launch_bounds__(256) void gemm_mfma_bf16(const AT* __restrict__ A,
                                                      const bf16* __restrict__ Bt,
                                                      bf16* __restrict__ Fb, int N) {
    constexpr int K = 256, BM = 128, BK = 32;
    constexpr int LDA = BK + 8;
    __shared__ bf16 As[BM * LDA];
    __shared__ bf16 Bs[BM * LDA];

    const int tid = threadIdx.x;
    const int wave = tid >> 6, lane = tid & 63;
    const int quad = lane >> 4, l16 = lane & 15;
    const int rowBase = blockIdx.y * BM;
    const int colBase = blockIdx.x * BM;
    const int m_base = (wave >> 1) * 64, n_base = (wave & 1) * 64;

    f32x4 acc[4][4] = {};

    const int sr = tid >> 1;
    const int seg = (tid & 1) << 4;

    for (int k0 = 0; k0 < K; k0 += BK) {
        {
            const int gr = rowBase + sr;
            if constexpr (std::is_same<AT, float>::value) {
                float4 f0 = {0,0,0,0}, f1 = {0,0,0,0}, f2 = {0,0,0,0}, f3 = {0,0,0,0};
                if (gr < N) {
                    const float4* Ag = (const float4*)(A + (long)gr * K + k0 + seg);
                    f0 = Ag[0]; f1 = Ag[1]; f2 = Ag[2]; f3 = Ag[3];
                }
                bf16x8 p0, p1;
                p0[0] = (bf16)f0.x; p0[1] = (bf16)f0.y; p0[2] = (bf16)f0.z; p0[3] = (bf16)f0.w;
                p0[4] = (bf16)f1.x; p0[5] = (bf16)f1.y; p0[6] = (bf16)f1.z; p0[7] = (bf16)f1.w;
                p1[0] = (bf16)f2.x; p1[1] = (bf16)f2.y; p1[2] = (bf16)f2.z; p1[3] = (bf16)f2.w;
                p1[4] = (bf16)f3.x; p1[5] = (bf16)f3.y; p1[6] = (bf16)f3.z; p1[7] = (bf16)f3.w;
                *(bf16x8*)&As[sr * LDA + seg] = p0;
                *(bf16x8*)&As[sr * LDA + seg + 8] = p1;
            } else {
                bf16x8 p0 = {}, p1 = {};
                if (gr < N) {
                    const bf16x8* Ag = (const bf16x8*)(A + (long)gr * K + k0 + seg);
                    p0 = Ag[0]; p1 = Ag[1];
                }
                *(bf16x8*)&As[sr * LDA + seg] = p0;
                *(bf16x8*)&As[sr * LDA + seg + 8] = p1;
            }
        }
        {
            const bf16x8* Bg = (const bf16x8*)(Bt + (long)(colBase + sr) * K + k0 + seg);
            *(bf16x8*)&Bs[sr * LDA + seg] = Bg[0];
            *(bf16x8*)&Bs[sr * LDA + seg + 8] = Bg[1];
        }
        __syncthreads();

        bf16x8 af[4], bfr[4];
#pragma unroll
        for (int mi = 0; mi < 4; mi++)
            af[mi] = *(const bf16x8*)&As[(m_base + mi * 16 + l16) * LDA + quad * 8];
#pragma unroll
        for (int ni = 0; ni < 4; ni++)
            bfr[ni] = *(const bf16x8*)&Bs[(n_base + ni * 16 + l16) * LDA + quad * 8];
#pragma unroll
        for (int mi = 0; mi < 4; mi++)
#pragma unroll
            for (int ni = 0; ni < 4; ni++)
                acc[mi][ni] = __builtin_amdgcn_mfma_f32_16x16x32_bf16(af[mi], bfr[ni], acc[mi][ni], 0, 0, 0);
        __syncthreads();
    }

    // epilogue: C/D layout col=lane&15, row=quad*4+reg [m89-verified]; write bf16
#pragma unroll
    for (int mi = 0; mi < 4; mi++) {
#pragma unroll
        for (int r = 0; r < 4; r++) {
            const int grow = rowBase + m_base + mi * 16 + quad * 4 + r;
            if (grow < N) {
#pragma unroll
                for (int ni = 0; ni < 4; ni++) {
                    Fb[(long)grow * 256 + colBase + n_base + ni * 16 + l16] = (bf16)acc[mi][ni][r];
                }
            }
        }
    }
}

// ---------------- MFMA GEMM narrow: C[N,32](fp32) = A[N,256](bf16) @ Bct^T --------
__global__ __launch_bounds__(256) void gemm_mfma_n32(const bf16* __restrict__ A,
                                                     const bf16* __restrict__ Bt,
                                                     float* __restrict__ C, int N) {
    constexpr int K = 256, BM = 128, BK = 32;
    constexpr int LDA = BK + 8;
    __shared__ bf16 As[BM * LDA];
    __shared__ bf16 Bs[32 * LDA];

    const int tid = threadIdx.x;
    const int wave = tid >> 6, lane = tid & 63;
    const int quad = lane >> 4, l16 = lane & 15;
    const int rowBase = blockIdx.x * BM;
    const int m_base = (wave >> 1) * 64, n_base = (wave & 1) * 16;

    f32x4 acc[4] = {};

    const int sr = tid >> 1;
    const int seg = (tid & 1) << 4;

    for (int k0 = 0; k0 < K; k0 += BK) {
        {
            const int gr = rowBase + sr;
            bf16x8 p0 = {}, p1 = {};
            if (gr < N) {
                const bf16x8* Ag = (const bf16x8*)(A + (long)gr * K + k0 + seg);
                p0 = Ag[0]; p1 = Ag[1];
            }
            *(bf16x8*)&As[sr * LDA + seg] = p0;
            *(bf16x8*)&As[sr * LDA + seg + 8] = p1;
        }
        if (tid < 64) {
            const int br = tid >> 1;
            const bf16x8* Bg = (const bf16x8*)(Bt + br * K + k0 + seg);
            *(bf16x8*)&Bs[br * LDA + seg] = Bg[0];
            *(bf16x8*)&Bs[br * LDA + seg + 8] = Bg[1];
        }
        __syncthreads();

        const bf16x8 bfr = *(const bf16x8*)&Bs[(n_base + l16) * LDA + quad * 8];
#pragma unroll
        for (int mi = 0; mi < 4; mi++) {
            const bf16x8 af = *(const bf16x8*)&As[(m_base + mi * 16 + l16) * LDA + quad * 8];
            acc[mi] = __builtin_amdgcn_mfma_f32_16x16x32_bf16(af, bfr, acc[mi], 0, 0, 0);
        }
        __syncthreads();
    }

#pragma unroll
    for (int mi = 0; mi < 4; mi++) {
#pragma unroll
        for (int r = 0; r < 4; r++) {
            const int grow = rowBase + m_base + mi * 16 + quad * 4 + r;
            if (grow < N) C[(long)grow * 32 + n_base + l16] = acc[mi][r];
        }
    }
}

// ---------------- el/er: one WAVE per node, all 4 heads ----------------
__global__ void el_er_node_kernel(const bf16* __restrict__ feat,
                                  const float* __restrict__ al, const float* __restrict__ ar,
                                  float* __restrict__ el, float* __restrict__ er, int N) {
    const int wid = (blockIdx.x * blockDim.x + threadIdx.x) >> 6;
    const int lane = threadIdx.x & 63;
    if (wid >= N) return;
    const bf16x4 f = ((const bf16x4*)feat)[(long)wid * 64 + lane];
    const float4 a = ((const float4*)al)[lane];
    const float4 b = ((const float4*)ar)[lane];
    const float f0 = (float)f[0], f1 = (float)f[1], f2 = (float)f[2], f3 = (float)f[3];
    float vl = f0 * a.x + f1 * a.y + f2 * a.z + f3 * a.w;
    float vr = f0 * b.x + f1 * b.y + f2 * b.z + f3 * b.w;
#pragma unroll
    for (int off = 1; off < 16; off <<= 1) {
        vl += __shfl_xor(vl, off);
        vr += __shfl_xor(vr, off);
    }
    if ((lane & 15) == 0) {
        const int h = lane >> 4;
        el[wid * 4 + h] = vl;
        er[wid * 4 + h] = vr;
    }
}

// el/er from fp32 feat with row stride (layer 2, H=1, D=16)
__global__ void el_er_strided16(const float* __restrict__ feat, int stride,
                                const float* __restrict__ al, const float* __restrict__ ar,
                                float* __restrict__ el, float* __restrict__ er, int N) {
    const int wid = (blockIdx.x * blockDim.x + threadIdx.x) >> 6;
    const int lane = threadIdx.x & 63;
    if (wid >= N) return;
    float vl = 0.f, vr = 0.f;
    if (lane < 16) {
        float f = feat[(long)wid * stride + lane];
        vl = f * al[lane];
        vr = f * ar[lane];
    }
#pragma unroll
    for (int off = 1; off < 16; off <<= 1) {
        vl += __shfl_xor(vl, off);
        vr += __shfl_xor(vr, off);
    }
    if (lane == 0) { el[wid] = vl; er[wid] = vr; }
}

// ---------------- global max of el (4 float-lanes) ----------------
__global__ void elmax4_kernel(const float4* __restrict__ el4, unsigned* __restrict__ elmax_u, int n4) {
    __shared__ float4 sm[256];
    float4 m = {-INFINITY, -INFINITY, -INFINITY, -INFINITY};
    for (int i = blockIdx.x * blockDim.x + threadIdx.x; i < n4; i += gridDim.x * blockDim.x) {
        const float4 v = el4[i];
        m.x = fmaxf(m.x, v.x); m.y = fmaxf(m.y, v.y);
        m.z = fmaxf(m.z, v.z); m.w = fmaxf(m.w, v.w);
    }
    sm[threadIdx.x] = m;
    __syncthreads();
    for (int off = 128; off > 0; off >>= 1) {
        if (threadIdx.x < off) {
            float4 o = sm[threadIdx.x + off];
            float4 c = sm[threadIdx.x];
            c.x = fmaxf(c.x, o.x); c.y = fmaxf(c.y, o.y);
            c.z = fmaxf(c.z, o.z); c.w = fmaxf(c.w, o.w);
            sm[threadIdx.x] = c;
        }
        __syncthreads();
    }
    if (threadIdx.x == 0) {
        const float4 r = sm[0];
        atomicMax(&elmax_u[0], f2s(r.x));
        atomicMax(&elmax_u[1], f2s(r.y));
        atomicMax(&elmax_u[2], f2s(r.z));
        atomicMax(&elmax_u[3], f2s(r.w));
    }
}

// ---------------- CSR build ----------------

__global__ void count_deg_kernel(const int* __restrict__ dst, int* __restrict__ deg, int E) {
    const int e = blockIdx.x * blockDim.x + threadIdx.x;
    if (e >= E) return;
    atomicAdd(&deg[dst[e]], 1);
}

__global__ void scan_block_kernel(const int* __restrict__ deg, int* __restrict__ scanned,
                                  int* __restrict__ block_sums, int N) {
    __shared__ int smem[256];
    const int tid = threadIdx.x;
    const int base = blockIdx.x * 1024 + tid * 4;
    int v[4];
#pragma unroll
    for (int i = 0; i < 4; i++) v[i] = (base + i < N) ? deg[base + i] : 0;
    const int tsum = v[0] + v[1] + v[2] + v[3];
    smem[tid] = tsum;
    __syncthreads();
    int acc = tsum;
    for (int off = 1; off < 256; off <<= 1) {
        const int t = (tid >= off) ? smem[tid - off] : 0;
        __syncthreads();
        acc += t;
        smem[tid] = acc;
        __syncthreads();
    }
    if (tid == 255) block_sums[blockIdx.x] = acc;
    int run = acc - tsum;
#pragma unroll
    for (int i = 0; i < 4; i++) {
        if (base + i < N) scanned[base + i] = run;
        run += v[i];
    }
}

// single wave: exclusive-scan block sums; also inits the 12 elmax slots
__global__ void scan_sums_kernel(int* __restrict__ block_sums, unsigned* __restrict__ elmax_u, int nb) {
    const int tid = threadIdx.x;
    if (tid < 12) elmax_u[tid] = f2s(-INFINITY);
    const int orig = (tid < nb) ? block_sums[tid] : 0;
    int v = orig;
#pragma unroll
    for (int off = 1; off < 64; off <<= 1) {
        const int t = __shfl_up(v, off);
        if (tid >= off) v += t;
    }
    if (tid < nb) block_sums[tid] = v - orig;
}

__global__ void apply_offsets_kernel(const int* __restrict__ scanned, const int* __restrict__ block_sums,
                                     int* __restrict__ row_ptr, int* __restrict__ cursor, int N, int E) {
    const int i = blockIdx.x * blockDim.x + threadIdx.x;
    if (i < N) {
        const int v = scanned[i] + block_sums[i >> 10];
        row_ptr[i] = v;
        cursor[i] = v;
    }
    if (i == 0) row_ptr[N] = E;
}

__global__ void scatter_kernel(const int* __restrict__ src, const int* __restrict__ dst,
                               int* __restrict__ cursor, int* __restrict__ csr_src, int E) {
    const int e = blockIdx.x * blockDim.x + threadIdx.x;
    if (e >= E) return;
    const int pos = atomicAdd(&cursor[dst[e]], 1);
    csr_src[pos] = src[e];
}

// ---------------- aggregate + INLINE softmax weights ----------------
// One wave per node. Per edge: w = __expf(leaky(el[s]+erd) - shift) computed in-lane
// (upper-bound shift = leaky(elmax + erd) >= e, leaky monotonic => exp <= 1; softmax
// ratio identical to reference). l accumulates denom (lanes of equal head identical).
template <int H, int D, bool ACT, typename RT, typename OT>
__global__ void gat_aggregate_wave(const int* __restrict__ row_ptr, const int* __restrict__ csr_src,
                                   const float* __restrict__ el, const float* __restrict__ er,
                                   const unsigned* __restrict__ elmax_u,
                                   const bf16* __restrict__ feat,
                                   const RT* __restrict__ res, const float* __restrict__ bias,
                                   OT* __restrict__ out, int N) {
    constexpr int C = H * D;       // 256
    constexpr int V = C / 4;       // 64 x 4-channel groups
    const int wave = threadIdx.x >> 6;
    const int lane = threadIdx.x & 63;
    int n = blockIdx.x * (blockDim.x >> 6) + wave;
    if (n >= N) return;
    n = __builtin_amdgcn_readfirstlane(n);
    const int h = lane >> 4;       // D=64: 16 lanes per head
    const bf16x4* feat4 = (const bf16x4*)feat;

    const float erd = er[n * H + h];
    float sh = s2f(elmax_u[h]) + erd;
    sh = (sh >= 0.f) ? sh : 0.2f * sh;

    float4 acc = {0.f, 0.f, 0.f, 0.f};
    float l = 0.f;
    int p = row_ptr[n];
    const int pend = row_ptr[n + 1];
    for (; p + 4 <= pend; p += 4) {
        const int s0 = csr_src[p + 0];
        const int s1 = csr_src[p + 1];
        const int s2 = csr_src[p + 2];
        const int s3 = csr_src[p + 3];
        float e0 = el[s0 * H + h] + erd;
        float e1 = el[s1 * H + h] + erd;
        float e2 = el[s2 * H + h] + erd;
        float e3 = el[s3 * H + h] + erd;
        e0 = (e0 >= 0.f) ? e0 : 0.2f * e0;
        e1 = (e1 >= 0.f) ? e1 : 0.2f * e1;
        e2 = (e2 >= 0.f) ? e2 : 0.2f * e2;
        e3 = (e3 >= 0.f) ? e3 : 0.2f * e3;
        const float w0 = __expf(e0 - sh);
        const float w1 = __expf(e1 - sh);
        const float w2 = __expf(e2 - sh);
        const float w3 = __expf(e3 - sh);
        const bf16x4 f0 = feat4[(long)s0 * V + lane];
        const bf16x4 f1 = feat4[(long)s1 * V + lane];
        const bf16x4 f2 = feat4[(long)s2 * V + lane];
        const bf16x4 f3 = feat4[(long)s3 * V + lane];
        l += w0 + w1 + w2 + w3;
        acc.x += w0 * (float)f0[0] + w1 * (float)f1[0] + w2 * (float)f2[0] + w3 * (float)f3[0];
        acc.y += w0 * (float)f0[1] + w1 * (float)f1[1] + w2 * (float)f2[1] + w3 * (float)f3[1];
        acc.z += w0 * (float)f0[2] + w1 * (float)f1[2] + w2 * (float)f2[2] + w3 * (float)f3[2];
        acc.w += w0 * (float)f0[3] + w1 * (float)f1[3] + w2 * (float)f2[3] + w3 * (float)f3[3];
    }
    for (; p < pend; ++p) {
        const int s = csr_src[p];
        float e = el[s * H + h] + erd;
        e = (e >= 0.f) ? e : 0.2f * e;
        const float w = __expf(e - sh);
        const bf16x4 f = feat4[(long)s * V + lane];
        l += w;
        acc.x += w * (float)f[0];
        acc.y += w * (float)f[1];
        acc.z += w * (float)f[2];
        acc.w += w * (float)f[3];
    }
    const float inv = (l > 0.f) ? 1.f / l : 0.f;
    acc.x *= inv; acc.y *= inv; acc.z *= inv; acc.w *= inv;

    float4 r;
    if constexpr (std::is_same<RT, float>::value) {
        r = ((const float4*)res)[(long)n * V + lane];
    } else {
        const bf16x4 rb = ((const bf16x4*)res)[(long)n * V + lane];
        r = make_float4((float)rb[0], (float)rb[1], (float)rb[2], (float)rb[3]);
    }
    const float4 bb = ((const float4*)bias)[lane];
    float v[4] = {acc.x + r.x + bb.x, acc.y + r.y + bb.y,
                  acc.z + r.z + bb.z, acc.w + r.w + bb.w};
    if (ACT) {
#pragma unroll
        for (int i = 0; i < 4; i++) {
            const float sp = (v[i] > 20.f) ? v[i] : log1pf(expf(v[i]));
            v[i] = v[i] * tanhf(sp);
        }
    }
    if constexpr (std::is_same<OT, float>::value) {
        float4 o = {v[0], v[1], v[2], v[3]};
        ((float4*)out)[(long)n * V + lane] = o;
    } else {
        bf16x4 o;
        o[0] = (bf16)v[0]; o[1] = (bf16)v[1]; o[2] = (bf16)v[2]; o[3] = (bf16)v[3];
        ((bf16x4*)out)[(long)n * V + lane] = o;
    }
}

// ---------------- small-C aggregate (layer 2) + inline weights -------------------
// One thread per channel (C=16), NPB nodes per block. Denom computed redundantly
// per thread (cheap); shift from global elmax slots 8..11.
template <bool ACT, int NPB>
__global__ void gat_aggregate_small(const int* __restrict__ row_ptr, const int* __restrict__ csr_src,
                                    const float* __restrict__ el, const float* __restrict__ er,
                                    const unsigned* __restrict__ elmax_u,
                                    const float* __restrict__ feat, int fstride,
                                    const float* __restrict__ res, int rstride,
                                    const float* __restrict__ bias, float* __restrict__ out, int N) {
    constexpr int C = 16;
    const int local = threadIdx.x % C;
    const int n = blockIdx.x * NPB + threadIdx.x / C;
    if (n >= N) return;
    const float mx = fmaxf(fmaxf(s2f(elmax_u[8]), s2f(elmax_u[9])),
                           fmaxf(s2f(elmax_u[10]), s2f(elmax_u[11])));
    const float erd = er[n];
    float sh = mx + erd;
    sh = (sh >= 0.f) ? sh : 0.2f * sh;

    float acc = 0.f, l = 0.f;
    int p = row_ptr[n];
    const int pend = row_ptr[n + 1];
    for (; p + 4 <= pend; p += 4) {
        const int s0 = csr_src[p + 0];
        const int s1 = csr_src[p + 1];
        const int s2 = csr_src[p + 2];
        const int s3 = csr_src[p + 3];
        float e0 = el[s0] + erd, e1 = el[s1] + erd, e2 = el[s2] + erd, e3 = el[s3] + erd;
        e0 = (e0 >= 0.f) ? e0 : 0.2f * e0;
        e1 = (e1 >= 0.f) ? e1 : 0.2f * e1;
        e2 = (e2 >= 0.f) ? e2 : 0.2f * e2;
        e3 = (e3 >= 0.f) ? e3 : 0.2f * e3;
        const float w0 = __expf(e0 - sh);
        const float w1 = __expf(e1 - sh);
        const float w2 = __expf(e2 - sh);
        const float w3 = __expf(e3 - sh);
        l += w0 + w1 + w2 + w3;
        acc += w0 * feat[(long)s0 * fstride + local] + w1 * feat[(long)s1 * fstride + local]
             + w2 * feat[(long)s2 * fstride + local] + w3 * feat[(long)s3 * fstride + local];
    }
    for (; p < pend; ++p) {
        const int s = csr_src[p];
        float e = el[s] + erd;
        e = (e >= 0.f) ? e : 0.2f * e;
        const float w = __expf(e - sh);
        l += w;
        acc += w * feat[(long)s * fstride + local];
    }
    const float inv = (l > 0.f) ? 1.f / l : 0.f;
    float v = acc * inv + res[(long)n * rstride + local] + bias[local];
    if (ACT) {
        const float sp = (v > 20.f) ? v : log1pf(expf(v));
        v = v * tanhf(sp);
    }
    out[(long)n * C + local] = v;
}

// ---------------- host orchestration ----------------

static inline int cdiv(long a, long b) { return (int)((a + b - 1) / b); }

extern "C" void kernel_launch(void* const* d_in, const int* in_sizes, int n_in,
                              void* d_out, int out_size, void* d_ws, size_t ws_size,
                              hipStream_t stream) {
    const float* x   = (const float*)d_in[0];
    const int*   src = (const int*)d_in[1];
    const int*   dst = (const int*)d_in[2];
    const float* W0  = (const float*)d_in[3];
    const float* al0 = (const float*)d_in[4];
    const float* ar0 = (const float*)d_in[5];
    const float* b0  = (const float*)d_in[6];
    const float* W1  = (const float*)d_in[7];
    const float* al1 = (const float*)d_in[8];
    const float* ar1 = (const float*)d_in[9];
    const float* b1  = (const float*)d_in[10];
    const float* W2  = (const float*)d_in[11];
    const float* al2 = (const float*)d_in[12];
    const float* ar2 = (const float*)d_in[13];
    const float* b2  = (const float*)d_in[14];
    const float* rW2 = (const float*)d_in[15];
    float* out = (float*)d_out;

    const int N = in_sizes[0] / 256;   // 50000
    const int E = in_sizes[1];         // 800000

    // workspace layout
    bf16* Wt0    = (bf16*)d_ws;               // 256*256 bf16
    bf16* Wt1    = Wt0 + 65536;               // 256*256 bf16
    bf16* Bct    = Wt1 + 65536;               // 32*256 bf16
    bf16* Fb     = Bct + 8192;                // N*256 bf16 feat
    bf16* Hb     = Fb + (long)N * 256;        // N*256 bf16 hidden
    float* F2    = (float*)(Hb + (long)N * 256);  // N*32 (layer2 feat | res)
    float* el    = F2 + (long)N * 32;         // N*4
    float* er    = el + (long)N * 4;          // N*4
    unsigned* elmax_u = (unsigned*)(er + (long)N * 4); // 12
    int* deg     = (int*)(elmax_u + 12);      // N
    int* scanned = deg + N;                   // N
    int* bsums   = scanned + N;               // 64
    int* row_ptr = bsums + 64;                // N+1
    int* cursor  = row_ptr + N + 1;           // N
    int* csr_src = cursor + N;                // E

    const int THREADS = 256;
    const int NB = cdiv(N, 1024);
    dim3 mfma_grid(2, cdiv(N, 128));

    // ---------- prep + CSR build (reused by all layers) ----------
    prep_weights_kernel<<<cdiv(65536, THREADS), THREADS, 0, stream>>>(W0, W1, W2, rW2, Wt0, Wt1, Bct);
    hipMemsetAsync(deg, 0, (size_t)N * 4, stream);
    count_deg_kernel<<<cdiv(E, THREADS), THREADS, 0, stream>>>(dst, deg, E);
    scan_block_kernel<<<NB, 256, 0, stream>>>(deg, scanned, bsums, N);
    scan_sums_kernel<<<1, 64, 0, stream>>>(bsums, elmax_u, NB);
    apply_offsets_kernel<<<cdiv(N, THREADS), THREADS, 0, stream>>>(scanned, bsums, row_ptr, cursor, N, E);
    scatter_kernel<<<cdiv(E, THREADS), THREADS, 0, stream>>>(src, dst, cursor, csr_src, E);

    // ================= Layer 0 (H=4, D=64), input x (fp32), out Hb (bf16) =========
    gemm_mfma_bf16<float><<<mfma_grid, 256, 0, stream>>>(x, Wt0, Fb, N);
    el_er_node_kernel<<<cdiv(N, 4), 256, 0, stream>>>(Fb, al0, ar0, el, er, N);
    elmax4_kernel<<<64, 256, 0, stream>>>((const float4*)el, elmax_u, N);
    gat_aggregate_wave<4, 64, true, float, bf16><<<cdiv(N, 4), 256, 0, stream>>>(
        row_ptr, csr_src, el, er, elmax_u, Fb, x, b0, Hb, N);

    // ================= Layer 1 (H=4, D=64), input Hb (bf16), in-place =============
    gemm_mfma_bf16<bf16><<<mfma_grid, 256, 0, stream>>>(Hb, Wt1, Fb, N);
    el_er_node_kernel<<<cdiv(N, 4), 256, 0, stream>>>(Fb, al1, ar1, el, er, N);
    elmax4_kernel<<<64, 256, 0, stream>>>((const float4*)el, elmax_u + 4, N);
    gat_aggregate_wave<4, 64, true, bf16, bf16><<<cdiv(N, 4), 256, 0, stream>>>(
        row_ptr, csr_src, el, er, elmax_u + 4, Fb, Hb, b1, Hb, N);

    // ================= Layer 2 (H=1, D=16): F2 = Hb @ [W2|rW2] =====================
    gemm_mfma_n32<<<cdiv(N, 128), 256, 0, stream>>>(Hb, Bct, F2, N);
    el_er_strided16<<<cdiv(N, 4), 256, 0, stream>>>(F2, 32, al2, ar2, el, er, N);
    elmax4_kernel<<<64, 256, 0, stream>>>((const float4*)el, elmax_u + 8, N / 4);
    gat_aggregate_small<false, 16><<<cdiv(N, 16), 256, 0, stream>>>(row_ptr, csr_src, el, er, elmax_u,
                                                                    F2, 32, F2 + 16, 32, b2, out, N);
}